// Round 1
// baseline (857.236 us; speedup 1.0000x reference)
//
#include <hip/hip_runtime.h>
#include <hip/hip_bf16.h>

#define CIN 128
#define NHEAD 8
#define CHD 16
#define KVOL 27

constexpr float EPS_BN = 1e-5f;
constexpr float EPS_NORM = 1e-12f;

// ---------------- Kernel 1: BN1 statistics (sum, sumsq of points@w1, 3 cols) ----
__global__ void k_bn1_stats(const float* __restrict__ points,
                            const float* __restrict__ w1,
                            float* __restrict__ stats1, int N) {
  float w[9];
#pragma unroll
  for (int i = 0; i < 9; ++i) w[i] = w1[i];
  float s[3] = {0.f, 0.f, 0.f}, ss[3] = {0.f, 0.f, 0.f};
  for (int n = blockIdx.x * blockDim.x + threadIdx.x; n < N;
       n += gridDim.x * blockDim.x) {
    float p0 = points[3 * n], p1 = points[3 * n + 1], p2 = points[3 * n + 2];
#pragma unroll
    for (int j = 0; j < 3; ++j) {
      float y = p0 * w[j] + p1 * w[3 + j] + p2 * w[6 + j];
      s[j] += y;
      ss[j] += y * y;
    }
  }
#pragma unroll
  for (int j = 0; j < 3; ++j) {
    for (int off = 32; off > 0; off >>= 1) {
      s[j] += __shfl_down(s[j], off);
      ss[j] += __shfl_down(ss[j], off);
    }
  }
  if ((threadIdx.x & 63) == 0) {
#pragma unroll
    for (int j = 0; j < 3; ++j) {
      atomicAdd(&stats1[j], s[j]);
      atomicAdd(&stats1[3 + j], ss[j]);
    }
  }
}

// ---------------- Kernel 2: BN2 statistics (sum, sumsq of h0@w2, 128 cols) -----
// block = 128 threads, thread c owns column c; block-stride over points.
__global__ void k_bn2_stats(const float* __restrict__ points,
                            const float* __restrict__ w1,
                            const float* __restrict__ g1,
                            const float* __restrict__ b1,
                            const float* __restrict__ w2,
                            const float* __restrict__ stats1,
                            float* __restrict__ stats2, int N) {
  int c = threadIdx.x;
  float w[9];
#pragma unroll
  for (int i = 0; i < 9; ++i) w[i] = w1[i];
  float sc1[3], sh1[3];
#pragma unroll
  for (int j = 0; j < 3; ++j) {
    float m = stats1[j] / (float)N;
    float var = stats1[3 + j] / (float)N - m * m;
    float sc = rsqrtf(var + EPS_BN) * g1[j];
    sc1[j] = sc;
    sh1[j] = b1[j] - m * sc;
  }
  float wc0 = w2[c], wc1 = w2[CIN + c], wc2 = w2[2 * CIN + c];
  float s = 0.f, ss = 0.f;
  for (int n = blockIdx.x; n < N; n += gridDim.x) {
    float p0 = points[3 * n], p1 = points[3 * n + 1], p2 = points[3 * n + 2];
    float h0 = fmaxf(p0 * w[0] + p1 * w[3] + p2 * w[6], 0.f);  // placeholder
    // recompute properly (bn applied before relu):
    float y0 = p0 * w[0] + p1 * w[3] + p2 * w[6];
    float y1 = p0 * w[1] + p1 * w[4] + p2 * w[7];
    float y2 = p0 * w[2] + p1 * w[5] + p2 * w[8];
    float a0 = fmaxf(y0 * sc1[0] + sh1[0], 0.f);
    float a1 = fmaxf(y1 * sc1[1] + sh1[1], 0.f);
    float a2 = fmaxf(y2 * sc1[2] + sh1[2], 0.f);
    (void)h0;
    float y = a0 * wc0 + a1 * wc1 + a2 * wc2;
    s += y;
    ss += y * y;
  }
  atomicAdd(&stats2[c], s);
  atomicAdd(&stats2[CIN + c], ss);
}

// ---------------- Kernel 3: normalized positional encodings ---------------------
__global__ void k_pn(const float* __restrict__ pos_enc, float* __restrict__ pn) {
  int t = blockIdx.x * blockDim.x + threadIdx.x;
  if (t >= KVOL * NHEAD) return;
  const float* src = pos_enc + t * CHD;
  float vals[CHD];
  float sum = 0.f;
#pragma unroll
  for (int i = 0; i < CHD; ++i) {
    vals[i] = src[i];
    sum += vals[i] * vals[i];
  }
  float inv = 1.f / fmaxf(sqrtf(sum), EPS_NORM);
#pragma unroll
  for (int i = 0; i < CHD; ++i) pn[t * CHD + i] = vals[i] * inv;
}

// ---------------- Kernel 4: per-point chain -> qn, v ---------------------------
// block = 256 threads, 16 points per block. thread t: c = t&127, half = t>>7.
__global__ __launch_bounds__(256) void k_qv(
    const float* __restrict__ points, const float* __restrict__ feats,
    const float* __restrict__ w1, const float* __restrict__ g1,
    const float* __restrict__ b1, const float* __restrict__ w2,
    const float* __restrict__ g2, const float* __restrict__ b2,
    const float* __restrict__ w3, const float* __restrict__ b3,
    const float* __restrict__ wq, const float* __restrict__ bq,
    const float* __restrict__ wv, const float* __restrict__ bv,
    const float* __restrict__ stats1, const float* __restrict__ stats2,
    float* __restrict__ qn, float* __restrict__ vout, int N) {
  __shared__ float h0s[16][4];
  __shared__ float h1s[16][CIN];
  __shared__ float xs[16][CIN];

  int t = threadIdx.x;
  int c = t & 127;
  int half = t >> 7;
  int base = blockIdx.x * 16;

  // h0 for the 16 points (threads 0..15)
  if (t < 16) {
    int n = base + t;
    float a0 = 0.f, a1 = 0.f, a2 = 0.f;
    if (n < N) {
      float p0 = points[3 * n], p1 = points[3 * n + 1], p2 = points[3 * n + 2];
#pragma unroll
      for (int j = 0; j < 3; ++j) {
        float m = stats1[j] / (float)N;
        float var = stats1[3 + j] / (float)N - m * m;
        float sc = rsqrtf(var + EPS_BN) * g1[j];
        float sh = b1[j] - m * sc;
        float y = p0 * w1[j] + p1 * w1[3 + j] + p2 * w1[6 + j];
        float a = fmaxf(y * sc + sh, 0.f);
        if (j == 0) a0 = a;
        if (j == 1) a1 = a;
        if (j == 2) a2 = a;
      }
    }
    h0s[t][0] = a0;
    h0s[t][1] = a1;
    h0s[t][2] = a2;
  }
  __syncthreads();

  // bn2 params for column c
  float m2 = stats2[c] / (float)N;
  float v2 = stats2[CIN + c] / (float)N - m2 * m2;
  float sc2 = rsqrtf(v2 + EPS_BN) * g2[c];
  float sh2 = b2[c] - m2 * sc2;
  float w2c0 = w2[c], w2c1 = w2[CIN + c], w2c2 = w2[2 * CIN + c];

#pragma unroll
  for (int i = 0; i < 8; ++i) {
    int p = i * 2 + half;
    float y = h0s[p][0] * w2c0 + h0s[p][1] * w2c1 + h0s[p][2] * w2c2;
    h1s[p][c] = fmaxf(y * sc2 + sh2, 0.f);
  }
  __syncthreads();

  // x = feats + h1@w3 + b3
  float acc[8];
  float b3c = b3[c];
#pragma unroll
  for (int i = 0; i < 8; ++i) acc[i] = b3c;
  for (int k = 0; k < CIN; ++k) {
    float w = w3[k * CIN + c];
#pragma unroll
    for (int i = 0; i < 8; ++i) acc[i] += h1s[i * 2 + half][k] * w;
  }
#pragma unroll
  for (int i = 0; i < 8; ++i) {
    int p = i * 2 + half;
    int n = base + p;
    float f = (n < N) ? feats[(size_t)n * CIN + c] : 0.f;
    xs[p][c] = acc[i] + f;
  }
  __syncthreads();

  // q, v
  float qa[8], va[8];
  float bqc = bq[c], bvc = bv[c];
#pragma unroll
  for (int i = 0; i < 8; ++i) {
    qa[i] = bqc;
    va[i] = bvc;
  }
  for (int k = 0; k < CIN; ++k) {
    float wqv = wq[k * CIN + c];
    float wvv = wv[k * CIN + c];
#pragma unroll
    for (int i = 0; i < 8; ++i) {
      float xv = xs[i * 2 + half][k];
      qa[i] += xv * wqv;
      va[i] += xv * wvv;
    }
  }

  // L2 norm per head (16-lane groups) and store
#pragma unroll
  for (int i = 0; i < 8; ++i) {
    float q = qa[i];
    float sum = q * q;
    sum += __shfl_xor(sum, 1);
    sum += __shfl_xor(sum, 2);
    sum += __shfl_xor(sum, 4);
    sum += __shfl_xor(sum, 8);
    float inv = 1.f / fmaxf(sqrtf(sum), EPS_NORM);
    int n = base + i * 2 + half;
    if (n < N) {
      qn[(size_t)n * CIN + c] = q * inv;
      vout[(size_t)n * CIN + c] = va[i];
    }
  }
}

// ---------------- Kernel 5: attention dot + scatter-add ------------------------
// 2 pairs per 256-thread block. thread t: m = blk*2 + (t>>7), c = t&127.
__global__ __launch_bounds__(256) void k_attn_scatter(
    const int* __restrict__ k_idx, const int* __restrict__ q_idx,
    const int* __restrict__ kernel_idx, const float* __restrict__ qn,
    const float* __restrict__ v, const float* __restrict__ pn,
    float* __restrict__ out, int M) {
  int t = threadIdx.x;
  int m = blockIdx.x * 2 + (t >> 7);
  if (m >= M) return;
  int c = t & 127;
  int qi = q_idx[m];
  int ki = k_idx[m];
  int kk = kernel_idx[m];
  float a = qn[(size_t)qi * CIN + c] * pn[kk * CIN + c];
  a += __shfl_xor(a, 1);
  a += __shfl_xor(a, 2);
  a += __shfl_xor(a, 4);
  a += __shfl_xor(a, 8);
  float val = a * v[(size_t)ki * CIN + c];
  atomicAdd(&out[(size_t)qi * CIN + c], val);
}

// ---------------- Kernel 6: out = acc @ wo + bo (in place on d_out) ------------
__global__ __launch_bounds__(256) void k_out(const float* __restrict__ wo,
                                             const float* __restrict__ bo,
                                             float* __restrict__ out, int N) {
  __shared__ float accs[16][CIN];
  int t = threadIdx.x;
  int c = t & 127;
  int half = t >> 7;
  int base = blockIdx.x * 16;
#pragma unroll
  for (int i = 0; i < 8; ++i) {
    int p = i * 2 + half;
    int n = base + p;
    accs[p][c] = (n < N) ? out[(size_t)n * CIN + c] : 0.f;
  }
  __syncthreads();
  float acc[8];
  float boc = bo[c];
#pragma unroll
  for (int i = 0; i < 8; ++i) acc[i] = boc;
  for (int k = 0; k < CIN; ++k) {
    float w = wo[k * CIN + c];
#pragma unroll
    for (int i = 0; i < 8; ++i) acc[i] += accs[i * 2 + half][k] * w;
  }
#pragma unroll
  for (int i = 0; i < 8; ++i) {
    int n = base + i * 2 + half;
    if (n < N) out[(size_t)n * CIN + c] = acc[i];
  }
}

// ---------------- launch -------------------------------------------------------
extern "C" void kernel_launch(void* const* d_in, const int* in_sizes, int n_in,
                              void* d_out, int out_size, void* d_ws,
                              size_t ws_size, hipStream_t stream) {
  const float* points = (const float*)d_in[0];
  const float* feats = (const float*)d_in[1];
  const int* k_idx = (const int*)d_in[2];
  const int* q_idx = (const int*)d_in[3];
  const int* kernel_idx = (const int*)d_in[4];
  const float* w1 = (const float*)d_in[5];
  const float* g1 = (const float*)d_in[6];
  const float* b1 = (const float*)d_in[7];
  const float* w2 = (const float*)d_in[8];
  const float* g2 = (const float*)d_in[9];
  const float* b2 = (const float*)d_in[10];
  const float* w3 = (const float*)d_in[11];
  const float* b3 = (const float*)d_in[12];
  const float* wq = (const float*)d_in[13];
  const float* bq = (const float*)d_in[14];
  const float* wv = (const float*)d_in[15];
  const float* bv = (const float*)d_in[16];
  const float* wo = (const float*)d_in[17];
  const float* bo = (const float*)d_in[18];
  const float* pos_enc = (const float*)d_in[19];

  int N = in_sizes[0] / 3;
  int M = in_sizes[2];

  float* ws = (float*)d_ws;
  float* stats1 = ws;                   // 8 floats (6 used)
  float* stats2 = ws + 8;               // 256 floats
  float* pn = ws + 8 + 256;             // 27*128 = 3456 floats
  float* qn = ws + 4096;                // N*128 floats
  float* vbuf = qn + (size_t)N * CIN;   // N*128 floats
  float* outf = (float*)d_out;

  // zero stats and output accumulator (required every call; harness poisons once)
  hipMemsetAsync(ws, 0, 4096 * sizeof(float), stream);
  hipMemsetAsync(d_out, 0, (size_t)N * CIN * sizeof(float), stream);

  k_bn1_stats<<<256, 256, 0, stream>>>(points, w1, stats1, N);
  k_bn2_stats<<<512, 128, 0, stream>>>(points, w1, g1, b1, w2, stats1, stats2, N);
  k_pn<<<1, 256, 0, stream>>>(pos_enc, pn);
  k_qv<<<(N + 15) / 16, 256, 0, stream>>>(points, feats, w1, g1, b1, w2, g2, b2,
                                          w3, b3, wq, bq, wv, bv, stats1, stats2,
                                          qn, vbuf, N);
  k_attn_scatter<<<(M + 1) / 2, 256, 0, stream>>>(k_idx, q_idx, kernel_idx, qn,
                                                  vbuf, pn, outf, M);
  k_out<<<(N + 15) / 16, 256, 0, stream>>>(wo, bo, outf, N);
}